// Round 12
// baseline (229.177 us; speedup 1.0000x reference)
//
#include <hip/hip_runtime.h>
#include <math.h>

#define Bn   2048
#define Ln   200
#define En   64
#define Vn   100000
#define FEATn 1664
#define LPAD 224     // 7 * 32

typedef short s4v __attribute__((ext_vector_type(4)));
typedef short s8v __attribute__((ext_vector_type(8)));
typedef float f4v __attribute__((ext_vector_type(4)));

__device__ __forceinline__ short f2bf(float f) {
  union { float f; unsigned u; } v; v.f = f;
  unsigned r = v.u + 0x7FFFu + ((v.u >> 16) & 1u);   // RNE
  return (short)(r >> 16);
}
__device__ __forceinline__ float bf2f(short s) {
  union { unsigned u; float f; } v;
  v.u = ((unsigned)(unsigned short)s) << 16;
  return v.f;
}
__device__ __forceinline__ unsigned pk2(float lo, float hi) {
  return ((unsigned)(unsigned short)f2bf(hi) << 16) | (unsigned short)f2bf(lo);
}

// pair-interleaved fragment k-mapping (A and B sides identical -> invariant):
// element jj holds k = ks*32 + lg*4 + (jj>>1) + 16*(jj&1)
// i.e. a b128 of 4 u32 pairs (k, k+16) feeds one s8v fragment directly.
__device__ __forceinline__ int frag_k(int ks, int lg, int jj) {
  return ks * 32 + lg * 4 + (jj >> 1) + ((jj & 1) << 4);
}

// ---------------- block-wide sum (256 threads = 4 waves) --------------------
__device__ __forceinline__ float blk_sum(float v, float* shred) {
  #pragma unroll
  for (int o = 32; o > 0; o >>= 1) v += __shfl_down(v, o, 64);
  const int t = threadIdx.x;
  __syncthreads();
  if ((t & 63) == 0) shred[t >> 6] = v;
  __syncthreads();
  return shred[0] + shred[1] + shred[2] + shred[3];
}

// ---------------- K0a: prep — fragment-ordered bf16 weights -----------------
__global__ __launch_bounds__(256) void k_prep(
    const float* __restrict__ A1, const float* __restrict__ A2,
    short* __restrict__ W1f, short* __restrict__ W2f, short* __restrict__ A1s)
{
  int i = blockIdx.x * 256 + threadIdx.x;
  if (i < 32768) {
    int jj = i & 7, lane = (i >> 3) & 63, nt = (i >> 9) & 3,
        ks = (i >> 11) & 3, w = (i >> 13) & 3;
    int col = w * 64 + nt * 16 + (lane & 15);
    int lg = lane >> 4;
    float v;
    if (ks < 2) {
      int k = frag_k(ks, lg, jj);
      v = A1[(64 + k) * 256 + col] - A1[(128 + k) * 256 + col];
    } else {
      int k = frag_k(ks - 2, lg, jj);
      v = A1[(192 + k) * 256 + col];
    }
    W1f[i] = f2bf(v);
  } else if (i < 65536) {
    int u = i - 32768;
    int jj = u & 7, lane = (u >> 3) & 63, nt = (u >> 9) & 1,
        ks = (u >> 10) & 7, w = (u >> 13) & 3;
    int col = w * 32 + nt * 16 + (lane & 15);
    int lg = lane >> 4;
    int k = frag_k(ks, lg, jj);
    W2f[u] = f2bf(A2[k * 128 + col]);
  } else if (i < 81920) {
    int u = i - 65536;
    int e = u >> 8, j = u & 255;
    A1s[u] = f2bf(A1[e * 256 + j] + A1[(128 + e) * 256 + j]);
  }
}

// ---------------- K0b: item_emb table 0 -> pair-interleaved bf16 copy -------
// row layout: 32 u32; col c holds (e, e+16) with e = (c&15) + ((c>>4)<<5)
__global__ __launch_bounds__(256) void k_cvt(
    const float* __restrict__ src, unsigned* __restrict__ dst, int nq)
{
  int q = blockIdx.x * 256 + threadIdx.x;
  if (q >= nq) return;
  int row = q >> 3, cq = (q & 7) << 2;       // 4 u32 per thread
  int e0 = (cq & 15) + ((cq >> 4) << 5);
  const float* rp = src + (size_t)row * 64 + e0;
  float4 lo = *(const float4*)rp;
  float4 hi = *(const float4*)(rp + 16);
  unsigned* d = dst + (size_t)row * 32 + cq;
  d[0] = pk2(lo.x, hi.x); d[1] = pk2(lo.y, hi.y);
  d[2] = pk2(lo.z, hi.z); d[3] = pk2(lo.w, hi.w);
}

// ---------------- K0c: D1/D2/D3 [K][N] f32 -> [N][K] bf16 -------------------
__global__ __launch_bounds__(256) void k_trcvt(
    const float* __restrict__ D1, const float* __restrict__ D2,
    const float* __restrict__ D3,
    short* __restrict__ T1, short* __restrict__ T2, short* __restrict__ T3)
{
  __shared__ float tile[32][33];
  int blk = blockIdx.x;
  const float* src; short* dst; int K, N, b0;
  if (blk < 832)      { src = D1; dst = T1; K = 1664; N = 512; b0 = blk; }
  else if (blk < 960) { src = D2; dst = T2; K = 512;  N = 256; b0 = blk - 832; }
  else                { src = D3; dst = T3; K = 256;  N = 256; b0 = blk - 960; }
  int nbk = K / 32;
  int kb = (b0 % nbk) * 32, nb = (b0 / nbk) * 32;
  int tx = threadIdx.x & 31, ty = threadIdx.x >> 5;   // ty 0..7
  #pragma unroll
  for (int i = 0; i < 4; i++)
    tile[ty + i * 8][tx] = src[(size_t)(kb + ty + i * 8) * N + nb + tx];
  __syncthreads();
  #pragma unroll
  for (int i = 0; i < 4; i++)
    dst[(size_t)(nb + ty + i * 8) * K + kb + tx] = f2bf(tile[tx][ty + i * 8]);
}

// ---------------- K1: small gathers + numeric proj + pools + qterm ----------
__global__ __launch_bounds__(256) void k_gather(
    const int* __restrict__ user_cat, const float* __restrict__ user_num,
    const int* __restrict__ ctx_cat,  const float* __restrict__ ctx_num,
    const int* __restrict__ item_cat, const float* __restrict__ item_num,
    const float* __restrict__ user_emb, const float* __restrict__ item_emb,
    const float* __restrict__ ctx_emb,
    const float* __restrict__ Wu, const float* __restrict__ bu,
    const float* __restrict__ Wi, const float* __restrict__ bi,
    const float* __restrict__ Wc, const float* __restrict__ bc,
    const int* __restrict__ hist_author, const int* __restrict__ hist_tag,
    const int* __restrict__ hist_mask,
    const short* __restrict__ A1s, const float* __restrict__ a1,
    float* __restrict__ base, short* __restrict__ baseb,
    float* __restrict__ qterm)
{
  __shared__ float sRed[8][64];
  __shared__ float sNv[4];
  __shared__ float sQ[64];
  const int b = blockIdx.x, t = threadIdx.x;
  float* out = base + (size_t)b * FEATn;
  short* outb = baseb + (size_t)b * FEATn;

  if (t < 64) sQ[t] = item_emb[(size_t)item_cat[b * 8] * 64 + t];

  for (int f = t; f < 1344; f += 256) {
    float v;
    if (f < 384) {
      int n = f >> 6, e = f & 63;
      int id = user_cat[b * 6 + n];
      v = user_emb[((size_t)n * Vn + id) * 64 + e];
    } else if (f < 896) {
      int g = f - 384; int n = g >> 6, e = g & 63;
      int id = item_cat[b * 8 + n];
      v = item_emb[((size_t)n * Vn + id) * 64 + e];
    } else if (f < 1152) {
      int g = f - 896; int n = g >> 6, e = g & 63;
      int id = ctx_cat[b * 4 + n];
      v = ctx_emb[((size_t)n * Vn + id) * 64 + e];
    } else {
      int g = f - 1152; int wch = g >> 6, e = g & 63;
      float s;
      if (wch == 0) {
        s = bu[e];
        #pragma unroll
        for (int d = 0; d < 8; d++) s += user_num[b * 8 + d] * Wu[d * 64 + e];
      } else if (wch == 1) {
        s = bi[e];
        #pragma unroll
        for (int d = 0; d < 6; d++) s += item_num[b * 6 + d] * Wi[d * 64 + e];
      } else {
        s = bc[e];
        #pragma unroll
        for (int d = 0; d < 4; d++) s += ctx_num[b * 4 + d] * Wc[d * 64 + e];
      }
      v = fmaxf(s, 0.f);
    }
    out[f] = v;
    outb[f] = f2bf(v);
  }

  const float* itemA = item_emb + (size_t)Vn * 64;
  const float* itemT = item_emb + (size_t)7 * Vn * 64;
  const int e = t & 63, wg = t >> 6;
  float aa = 0.f, tg = 0.f, nv = 0.f;
  for (int l = wg; l < Ln; l += 4) {
    if (hist_mask[b * Ln + l] > 0) {      // wave-uniform
      aa += itemA[(size_t)hist_author[b * Ln + l] * 64 + e];
      tg += itemT[(size_t)hist_tag[b * Ln + l] * 64 + e];
      nv += 1.f;
    }
  }
  sRed[wg][e] = aa; sRed[4 + wg][e] = tg;
  if (e == 0) sNv[wg] = nv;
  __syncthreads();
  if (t < 64) {
    float ap = sRed[0][t] + sRed[1][t] + sRed[2][t] + sRed[3][t];
    float tp = sRed[4][t] + sRed[5][t] + sRed[6][t] + sRed[7][t];
    float nvalid = sNv[0] + sNv[1] + sNv[2] + sNv[3];
    float inv = 1.f / fmaxf(nvalid, 1e-6f);
    float apv = ap * inv, tpv = tp * inv;
    out[1408 + t] = apv;  outb[1408 + t] = f2bf(apv);
    out[1472 + t] = tpv;  outb[1472 + t] = f2bf(tpv);
  }

  { // qterm[b][t] = a1[t] + sum_e q[e] * A1sum[e][t]
    float s = a1[t];
    #pragma unroll 8
    for (int ee = 0; ee < 64; ee++) s += sQ[ee] * bf2f(A1s[ee * 256 + t]);
    qterm[(size_t)b * 256 + t] = s;
  }
}

// ---------------- K2: fused DIN attention (bf16 MFMA, pair-interleaved LDS) -
// One b per block (round-7 lesson: BPB loop + resident weights -> 216 VGPR,
// 1 wave/SIMD). sH staged from interleaved bf16 table (raw 16B copies).
// All fragments are single ds_read_b128; layer-1 output packed ds_write_b32.
__global__ __launch_bounds__(256) void k_attn(
    const int* __restrict__ hist_ids, const int* __restrict__ hist_mask,
    const unsigned* __restrict__ emb0u,
    const short* __restrict__ W1f, const short* __restrict__ W2f,
    const float* __restrict__ qterm,
    const float* __restrict__ a2, const float* __restrict__ A3,
    const float* __restrict__ a3,
    float* __restrict__ base, short* __restrict__ baseb)
{
  const int t = threadIdx.x;
  const int w = t >> 6, lane = t & 63, ln = lane & 15, lg = lane >> 4;
  const int b = blockIdx.x;

  __shared__ unsigned sHu[LPAD * 32] __attribute__((aligned(16)));   // 28 KB swz
  __shared__ unsigned sH1u[32 * 128] __attribute__((aligned(16)));   // 16 KB swz
  __shared__ float sScoreW[4][LPAD];
  __shared__ float sScore[LPAD];
  __shared__ int   sHid[LPAD];
  __shared__ float sQ[64];
  __shared__ float sRed[4][64];

  if (t < 64)  sQ[t] = base[(size_t)b * FEATn + 384 + t];
  if (t < LPAD) sHid[t] = (t < Ln) ? hist_ids[b * Ln + t] : 0;
  __syncthreads();

  // stage all history rows (interleaved bf16 table -> LDS, raw copies)
  #pragma unroll
  for (int it = 0; it < 7; it++) {
    int u = t + it * 256;
    int row = u >> 3, seg = (u & 7) << 2;     // 4-u32 chunk
    int4 hv = make_int4(0, 0, 0, 0);
    if (row < Ln)
      hv = *(const int4*)(emb0u + (size_t)sHid[row] * 32 + seg);
    *(int4*)(sHu + row * 32 + (seg ^ ((row & 7) << 2))) = hv;
  }

  // per-b fused layer-1 weights (K=64): W1c = W1h + diag(q)*W1q
  s8v bw1c[2][4];
  #pragma unroll
  for (int ks = 0; ks < 2; ks++) {
    float qk[8];
    #pragma unroll
    for (int jj = 0; jj < 8; jj++) qk[jj] = sQ[frag_k(ks, lg, jj)];
    #pragma unroll
    for (int nt = 0; nt < 4; nt++) {
      s8v fh = *(const s8v*)(W1f + (((w * 4 + ks) * 4 + nt) << 9) + lane * 8);
      s8v fq = *(const s8v*)(W1f + (((w * 4 + ks + 2) * 4 + nt) << 9) + lane * 8);
      s8v fc;
      #pragma unroll
      for (int jj = 0; jj < 8; jj++)
        fc[jj] = f2bf(bf2f(fh[jj]) + qk[jj] * bf2f(fq[jj]));
      bw1c[ks][nt] = fc;
    }
  }
  s8v bw2[8][2];
  #pragma unroll
  for (int ks = 0; ks < 8; ks++)
    #pragma unroll
    for (int nt = 0; nt < 2; nt++)
      bw2[ks][nt] = *(const s8v*)(W2f + (((w * 8 + ks) * 2 + nt) << 9) + lane * 8);

  const float a2v0 = a2[w * 32 + ln], a2v1 = a2[w * 32 + 16 + ln];
  const float a3v0 = A3[w * 32 + ln], a3v1 = A3[w * 32 + 16 + ln];
  const float a3s  = a3[0];
  float qt[4];
  #pragma unroll
  for (int i = 0; i < 4; i++)
    qt[i] = qterm[(size_t)b * 256 + w * 64 + i * 16 + ln];
  __syncthreads();

  for (int l0i = 0; l0i < 7; l0i++) {
    // ---- layer 1 (K=64, fused weights); A-frag = one b128 -----------------
    #pragma unroll
    for (int mt = 0; mt < 2; mt++) {
      f4v acc1[4];
      #pragma unroll
      for (int nt = 0; nt < 4; nt++)
        acc1[nt] = (f4v){qt[nt], qt[nt], qt[nt], qt[nt]};
      {
        int row = l0i * 32 + mt * 16 + ln;
        int swz = (row & 7) << 2;
        const unsigned* rp = sHu + row * 32;
        #pragma unroll
        for (int ks = 0; ks < 2; ks++) {
          s8v hf = *(const s8v*)(rp + ((ks * 16 + lg * 4) ^ swz));
          #pragma unroll
          for (int nt = 0; nt < 4; nt++)
            acc1[nt] = __builtin_amdgcn_mfma_f32_16x16x32_bf16(hf, bw1c[ks][nt], acc1[nt], 0, 0, 0);
        }
      }
      // relu + pack pairs (j, j+16) -> u32, 8 ds_write_b32 per mt
      #pragma unroll
      for (int h = 0; h < 2; h++)
        #pragma unroll
        for (int r = 0; r < 4; r++) {
          int row = mt * 16 + lg * 4 + r;
          int c = (w * 2 + h) * 16 + ln;
          sH1u[row * 128 + (c ^ ((row & 7) << 2))] =
              pk2(fmaxf(acc1[2 * h][r], 0.f), fmaxf(acc1[2 * h + 1][r], 0.f));
        }
    }
    __syncthreads();

    // ---- layer 2 + layer 3 partials (deferred cross-wave reduce) ----------
    #pragma unroll
    for (int mt = 0; mt < 2; mt++) {
      f4v acc2[2];
      acc2[0] = (f4v){a2v0, a2v0, a2v0, a2v0};
      acc2[1] = (f4v){a2v1, a2v1, a2v1, a2v1};
      {
        int row = mt * 16 + ln;
        int swz = (row & 7) << 2;
        const unsigned* rp = sH1u + row * 128;
        #pragma unroll
        for (int ks = 0; ks < 8; ks++) {
          s8v af = *(const s8v*)(rp + ((ks * 16 + lg * 4) ^ swz));
          acc2[0] = __builtin_amdgcn_mfma_f32_16x16x32_bf16(af, bw2[ks][0], acc2[0], 0, 0, 0);
          acc2[1] = __builtin_amdgcn_mfma_f32_16x16x32_bf16(af, bw2[ks][1], acc2[1], 0, 0, 0);
        }
      }
      #pragma unroll
      for (int r = 0; r < 4; r++) {
        float s = fmaxf(acc2[0][r], 0.f) * a3v0 + fmaxf(acc2[1][r], 0.f) * a3v1;
        s += __shfl_xor(s, 1, 64);
        s += __shfl_xor(s, 2, 64);
        s += __shfl_xor(s, 4, 64);
        s += __shfl_xor(s, 8, 64);
        if (ln == 0) sScoreW[w][l0i * 32 + mt * 16 + lg * 4 + r] = s;
      }
    }
    __syncthreads();                    // sH1 WAR for next tile
  }

  // ---- softmax by wave 0 (reduces the 4 wave partials inline) -------------
  if (w == 0) {
    float s[4], e[4];
    float mx = -3.0e38f;
    #pragma unroll
    for (int i = 0; i < 4; i++) {
      int l = lane + i * 64;
      bool valid = (l < Ln) && (hist_mask[(size_t)b * Ln + l] > 0);
      float sc = a3s + sScoreW[0][l] + sScoreW[1][l] + sScoreW[2][l] + sScoreW[3][l];
      s[i] = valid ? sc : -3.0e38f;
      mx = fmaxf(mx, s[i]);
    }
    #pragma unroll
    for (int o = 1; o < 64; o <<= 1) mx = fmaxf(mx, __shfl_xor(mx, o, 64));
    float sum = 0.f;
    #pragma unroll
    for (int i = 0; i < 4; i++) {
      e[i] = (s[i] > -1.0e38f) ? expf(s[i] - mx) : 0.f;
      sum += e[i];
    }
    #pragma unroll
    for (int o = 1; o < 64; o <<= 1) sum += __shfl_xor(sum, o, 64);
    float invS = 1.f / fmaxf(sum, 1e-30f);
    #pragma unroll
    for (int i = 0; i < 4; i++) {
      int l = lane + i * 64;
      if (l < LPAD) sScore[l] = e[i] * invS;
    }
  }
  __syncthreads();

  // ---- hist_att from LDS (masked weights exactly 0; interleaved extract) --
  {
    const int e = t & 63, wg = t >> 6;
    const int c = (e & 15) + ((e >> 5) << 4);
    const int hi = (e >> 4) & 1;
    float aw = 0.f;
    for (int l = wg; l < Ln; l += 4) {
      unsigned v = sHu[l * 32 + (c ^ ((l & 7) << 2))];
      short bf = (short)(hi ? (v >> 16) : (v & 0xffffu));
      aw += sScore[l] * bf2f(bf);
    }
    sRed[wg][e] = aw;
  }
  __syncthreads();
  if (t < 64) {
    float ha = sRed[0][t] + sRed[1][t] + sRed[2][t] + sRed[3][t];
    float tv = sQ[t];
    float* out = base + (size_t)b * FEATn;
    short* outb = baseb + (size_t)b * FEATn;
    float v1 = ha, v2 = tv * ha, v3 = tv - ha;
    out[1344 + t] = v1;  outb[1344 + t] = f2bf(v1);
    out[1536 + t] = v2;  outb[1536 + t] = f2bf(v2);
    out[1600 + t] = v3;  outb[1600 + t] = f2bf(v3);
  }
}

// ---------------- K3: bf16 MFMA GEMM  C = act(A @ W + bias) ------------------
// A: MxK bf16 row-major. Wt: NxK bf16 row-major (pre-transposed weights).
// Computes C^T tiles so the C-store is 4 consecutive n per lane.
__global__ __launch_bounds__(256) void k_gemm_mfma(
    const short* __restrict__ A, const short* __restrict__ Wt,
    const float* __restrict__ bias, void* __restrict__ C,
    int N, int K, int relu, int outbf)
{
  __shared__ short sA[64 * 32] __attribute__((aligned(16)));
  __shared__ short sW[64 * 32] __attribute__((aligned(16)));
  const int t = threadIdx.x;
  const int w = t >> 6, lane = t & 63, ln = lane & 15, lg = lane >> 4;
  const int m0 = blockIdx.x * 64, n0 = blockIdx.y * 64;
  const int wm = (w & 1) * 32, wn = (w >> 1) * 32;

  f4v acc[2][2] = {{(f4v){0,0,0,0},(f4v){0,0,0,0}},{(f4v){0,0,0,0},(f4v){0,0,0,0}}};

  for (int k0 = 0; k0 < K; k0 += 32) {
    #pragma unroll
    for (int i = 0; i < 2; i++) {
      int idx = t + i * 256;
      int r = idx >> 3, c = (idx & 7) << 2;
      s4v av = *(const s4v*)(A + (size_t)(m0 + r) * K + k0 + c);
      *(s4v*)(sA + ((r * 32 + c) ^ ((r & 7) << 2))) = av;
      s4v wv = *(const s4v*)(Wt + (size_t)(n0 + r) * K + k0 + c);
      *(s4v*)(sW + ((r * 32 + c) ^ ((r & 7) << 2))) = wv;
    }
    __syncthreads();

    s8v af[2], wf[2];
    #pragma unroll
    for (int mt = 0; mt < 2; mt++) {
      int row = wm + mt * 16 + ln;
      int idx = row * 32 + lg * 4, swz = (row & 7) << 2;
      s4v h0 = *(const s4v*)(sA + (idx ^ swz));
      s4v h1 = *(const s4v*)(sA + ((idx + 16) ^ swz));
      af[mt] = __builtin_shufflevector(h0, h1, 0,1,2,3,4,5,6,7);
    }
    #pragma unroll
    for (int nt = 0; nt < 2; nt++) {
      int row = wn + nt * 16 + ln;
      int idx = row * 32 + lg * 4, swz = (row & 7) << 2;
      s4v h0 = *(const s4v*)(sW + (idx ^ swz));
      s4v h1 = *(const s4v*)(sW + ((idx + 16) ^ swz));
      wf[nt] = __builtin_shufflevector(h0, h1, 0,1,2,3,4,5,6,7);
    }
    #pragma unroll
    for (int mt = 0; mt < 2; mt++)
      #pragma unroll
      for (int nt = 0; nt < 2; nt++)
        acc[mt][nt] = __builtin_amdgcn_mfma_f32_16x16x32_bf16(wf[nt], af[mt], acc[mt][nt], 0, 0, 0);
    __syncthreads();
  }

  // D[row=n][col=m]: lane(ln,lg): n = wn+nt*16+lg*4+r, m = wm+mt*16+ln
  #pragma unroll
  for (int mt = 0; mt < 2; mt++)
    #pragma unroll
    for (int nt = 0; nt < 2; nt++) {
      int n = n0 + wn + nt * 16 + lg * 4;
      int m = m0 + wm + mt * 16 + ln;
      float4 bz = *(const float4*)(bias + n);
      float4 o;
      o.x = acc[mt][nt][0] + bz.x; o.y = acc[mt][nt][1] + bz.y;
      o.z = acc[mt][nt][2] + bz.z; o.w = acc[mt][nt][3] + bz.w;
      if (relu) {
        o.x = fmaxf(o.x, 0.f); o.y = fmaxf(o.y, 0.f);
        o.z = fmaxf(o.z, 0.f); o.w = fmaxf(o.w, 0.f);
      }
      if (outbf) {
        s4v o4 = { f2bf(o.x), f2bf(o.y), f2bf(o.z), f2bf(o.w) };
        *(s4v*)((short*)C + (size_t)m * N + n) = o4;
      } else {
        *(float4*)((float*)C + (size_t)m * N + n) = o;
      }
    }
}

// ---------------- K4: DCN cross (3 iters) + final head ----------------------
__global__ __launch_bounds__(256) void k_cross_final(
    const float* __restrict__ base, const float* __restrict__ cross_w,
    const float* __restrict__ cross_b, const float* __restrict__ deep3,
    const float* __restrict__ Wh, const float* __restrict__ bh,
    float* __restrict__ out)
{
  __shared__ float shred[4];
  const int b = blockIdx.x, t = threadIdx.x;
  const float* br = base + (size_t)b * FEATn;
  float bs[7], xl[7];
  #pragma unroll
  for (int j = 0; j < 7; j++) {
    int i = t + j * 256;
    float v = (i < FEATn) ? br[i] : 0.f;
    bs[j] = v; xl[j] = v;
  }
  for (int k = 0; k < 3; k++) {
    float p = 0.f;
    #pragma unroll
    for (int j = 0; j < 7; j++) {
      int i = t + j * 256;
      if (i < FEATn) p += xl[j] * cross_w[k * FEATn + i];
    }
    float xw = blk_sum(p, shred);
    #pragma unroll
    for (int j = 0; j < 7; j++) {
      int i = t + j * 256;
      if (i < FEATn) xl[j] = bs[j] * xw + cross_b[k * FEATn + i] + xl[j];
    }
  }
  float p = 0.f;
  #pragma unroll
  for (int j = 0; j < 7; j++) {
    int i = t + j * 256;
    if (i < FEATn) p += xl[j] * Wh[i];
  }
  p += deep3[(size_t)b * 256 + t] * Wh[FEATn + t];
  float tot = blk_sum(p, shred);
  if (t == 0) out[b] = tot + bh[0];
}

// ---------------- launch -----------------------------------------------------
extern "C" void kernel_launch(void* const* d_in, const int* in_sizes, int n_in,
                              void* d_out, int out_size, void* d_ws, size_t ws_size,
                              hipStream_t stream) {
  (void)in_sizes; (void)n_in; (void)out_size; (void)ws_size;
  const int*   user_cat  = (const int*)d_in[0];
  const float* user_num  = (const float*)d_in[1];
  const int*   ctx_cat   = (const int*)d_in[2];
  const float* ctx_num   = (const float*)d_in[3];
  const int*   hist_ids  = (const int*)d_in[4];
  const int*   hist_auth = (const int*)d_in[5];
  const int*   hist_tag  = (const int*)d_in[6];
  const int*   hist_mask = (const int*)d_in[7];
  const int*   item_cat  = (const int*)d_in[8];
  const float* item_num  = (const float*)d_in[9];
  const float* user_emb  = (const float*)d_in[10];
  const float* item_emb  = (const float*)d_in[11];
  const float* ctx_emb   = (const float*)d_in[12];
  const float* Wu = (const float*)d_in[13];  const float* bu = (const float*)d_in[14];
  const float* Wi = (const float*)d_in[15];  const float* bi = (const float*)d_in[16];
  const float* Wc = (const float*)d_in[17];  const float* bc = (const float*)d_in[18];
  const float* A1 = (const float*)d_in[19];  const float* a1 = (const float*)d_in[20];
  const float* A2 = (const float*)d_in[21];  const float* a2 = (const float*)d_in[22];
  const float* A3 = (const float*)d_in[23];  const float* a3 = (const float*)d_in[24];
  const float* cross_w = (const float*)d_in[25];
  const float* cross_b = (const float*)d_in[26];
  const float* D1 = (const float*)d_in[27];  const float* d1 = (const float*)d_in[28];
  const float* D2 = (const float*)d_in[29];  const float* d2 = (const float*)d_in[30];
  const float* D3 = (const float*)d_in[31];  const float* d3 = (const float*)d_in[32];
  const float* Wh = (const float*)d_in[33];  const float* bh = (const float*)d_in[34];

  // workspace (all segment sizes keep 16B alignment)
  float* base  = (float*)d_ws;                          // B x 1664 f32
  float* h3    = base + (size_t)Bn * FEATn;             // B x 256 f32
  float* qterm = h3 + (size_t)Bn * 256;                 // B x 256 f32
  short* baseb = (short*)(qterm + (size_t)Bn * 256);    // B x 1664 bf16
  short* h1b   = baseb + (size_t)Bn * FEATn;            // B x 512 bf16
  short* h2b   = h1b + (size_t)Bn * 512;                // B x 256 bf16
  short* W1f   = h2b + (size_t)Bn * 256;                // 32768
  short* W2f   = W1f + 32768;                           // 32768
  short* A1s   = W2f + 32768;                           // 16384
  unsigned* emb0u = (unsigned*)(A1s + 16384);           // Vn x 32 u32 (pair-interleaved)
  short* D1t   = (short*)(emb0u + (size_t)Vn * 32);     // 512 x 1664
  short* D2t   = D1t + (size_t)512 * 1664;              // 256 x 512
  short* D3t   = D2t + (size_t)256 * 512;               // 256 x 256

  k_prep<<<320, 256, 0, stream>>>(A1, A2, W1f, W2f, A1s);
  k_cvt<<<(Vn * 8 + 255) / 256, 256, 0, stream>>>(item_emb, emb0u, Vn * 8);
  k_trcvt<<<1024, 256, 0, stream>>>(D1, D2, D3, D1t, D2t, D3t);
  k_gather<<<Bn, 256, 0, stream>>>(user_cat, user_num, ctx_cat, ctx_num,
                                   item_cat, item_num, user_emb, item_emb, ctx_emb,
                                   Wu, bu, Wi, bi, Wc, bc,
                                   hist_auth, hist_tag, hist_mask,
                                   A1s, a1, base, baseb, qterm);
  k_attn<<<Bn, 256, 0, stream>>>(hist_ids, hist_mask, emb0u,
                                 W1f, W2f, qterm, a2, A3, a3, base, baseb);
  k_gemm_mfma<<<dim3(Bn / 64, 512 / 64), 256, 0, stream>>>(baseb, D1t, d1, h1b, 512, FEATn, 1, 1);
  k_gemm_mfma<<<dim3(Bn / 64, 256 / 64), 256, 0, stream>>>(h1b, D2t, d2, h2b, 256, 512, 1, 1);
  k_gemm_mfma<<<dim3(Bn / 64, 256 / 64), 256, 0, stream>>>(h2b, D3t, d3, h3, 256, 256, 0, 0);
  k_cross_final<<<Bn, 256, 0, stream>>>(base, cross_w, cross_b, h3, Wh, bh,
                                        (float*)d_out);
}

// Round 13
// 228.711 us; speedup vs baseline: 1.0020x; 1.0020x over previous
//
#include <hip/hip_runtime.h>
#include <hip/hip_bf16.h>
#include <math.h>

#define Bn   2048
#define Ln   200
#define En   64
#define Vn   100000
#define FEATn 1664
#define LPAD 224     // 7 * 32
#define HROWS 128    // l-rows per mlp half-block

typedef short s4v __attribute__((ext_vector_type(4)));
typedef short s8v __attribute__((ext_vector_type(8)));
typedef float f4v __attribute__((ext_vector_type(4)));

__device__ __forceinline__ short f2bf(float f) {
  union { float f; unsigned u; } v; v.f = f;
  unsigned r = v.u + 0x7FFFu + ((v.u >> 16) & 1u);   // RNE
  return (short)(r >> 16);
}
__device__ __forceinline__ float bf2f(short s) {
  union { unsigned u; float f; } v;
  v.u = ((unsigned)(unsigned short)s) << 16;
  return v.f;
}
__device__ __forceinline__ unsigned pk2(float lo, float hi) {
  __hip_bfloat162 h = __float22bfloat162_rn(make_float2(lo, hi));  // native v_cvt_pk
  union { __hip_bfloat162 h; unsigned u; } c; c.h = h;
  return c.u;
}

// pair-interleaved fragment k-mapping (A and B sides identical -> invariant):
// element jj holds k = ks*32 + lg*4 + (jj>>1) + 16*(jj&1)
__device__ __forceinline__ int frag_k(int ks, int lg, int jj) {
  return ks * 32 + lg * 4 + (jj >> 1) + ((jj & 1) << 4);
}

// ---------------- block-wide sum (256 threads = 4 waves) --------------------
__device__ __forceinline__ float blk_sum(float v, float* shred) {
  #pragma unroll
  for (int o = 32; o > 0; o >>= 1) v += __shfl_down(v, o, 64);
  const int t = threadIdx.x;
  __syncthreads();
  if ((t & 63) == 0) shred[t >> 6] = v;
  __syncthreads();
  return shred[0] + shred[1] + shred[2] + shred[3];
}

// ---------------- K0: merged prep (weights frags + emb cvt + deep transpose) -
__global__ __launch_bounds__(256) void k_prep_all(
    const float* __restrict__ A1, const float* __restrict__ A2,
    const float* __restrict__ item_emb,
    const float* __restrict__ D1, const float* __restrict__ D2,
    const float* __restrict__ D3,
    short* __restrict__ W1f, short* __restrict__ W2f, short* __restrict__ A1s,
    unsigned* __restrict__ emb0u,
    short* __restrict__ T1, short* __restrict__ T2, short* __restrict__ T3)
{
  const int blk = blockIdx.x;
  if (blk < 320) {                       // --- weight fragments + A1sum ---
    int i = blk * 256 + threadIdx.x;
    if (i < 32768) {
      int jj = i & 7, lane = (i >> 3) & 63, nt = (i >> 9) & 3,
          ks = (i >> 11) & 3, w = (i >> 13) & 3;
      int col = w * 64 + nt * 16 + (lane & 15);
      int lg = lane >> 4;
      float v;
      if (ks < 2) {
        int k = frag_k(ks, lg, jj);
        v = A1[(64 + k) * 256 + col] - A1[(128 + k) * 256 + col];
      } else {
        int k = frag_k(ks - 2, lg, jj);
        v = A1[(192 + k) * 256 + col];
      }
      W1f[i] = f2bf(v);
    } else if (i < 65536) {
      int u = i - 32768;
      int jj = u & 7, lane = (u >> 3) & 63, nt = (u >> 9) & 1,
          ks = (u >> 10) & 7, w = (u >> 13) & 3;
      int col = w * 32 + nt * 16 + (lane & 15);
      int lg = lane >> 4;
      int k = frag_k(ks, lg, jj);
      W2f[u] = f2bf(A2[k * 128 + col]);
    } else if (i < 81920) {
      int u = i - 65536;
      int e = u >> 8, j = u & 255;
      A1s[u] = f2bf(A1[e * 256 + j] + A1[(128 + e) * 256 + j]);
    }
  } else if (blk < 3445) {               // --- item_emb table0 -> interleaved bf16
    int q = (blk - 320) * 256 + threadIdx.x;   // q < 800000 exactly
    int row = q >> 3, cq = (q & 7) << 2;
    int e0 = (cq & 15) + ((cq >> 4) << 5);
    const float* rp = item_emb + (size_t)row * 64 + e0;
    float4 lo = *(const float4*)rp;
    float4 hi = *(const float4*)(rp + 16);
    unsigned* d = emb0u + (size_t)row * 32 + cq;
    d[0] = pk2(lo.x, hi.x); d[1] = pk2(lo.y, hi.y);
    d[2] = pk2(lo.z, hi.z); d[3] = pk2(lo.w, hi.w);
  } else {                               // --- D1/D2/D3 [K][N] -> [N][K] bf16
    __shared__ float tile[32][33];
    int b0 = blk - 3445;
    const float* src; short* dst; int K, N;
    if (b0 < 832)      { src = D1; dst = T1; K = 1664; N = 512; }
    else if (b0 < 960) { src = D2; dst = T2; K = 512;  N = 256; b0 -= 832; }
    else               { src = D3; dst = T3; K = 256;  N = 256; b0 -= 960; }
    int nbk = K / 32;
    int kb = (b0 % nbk) * 32, nb = (b0 / nbk) * 32;
    int tx = threadIdx.x & 31, ty = threadIdx.x >> 5;
    #pragma unroll
    for (int i = 0; i < 4; i++)
      tile[ty + i * 8][tx] = src[(size_t)(kb + ty + i * 8) * N + nb + tx];
    __syncthreads();
    #pragma unroll
    for (int i = 0; i < 4; i++)
      dst[(size_t)(nb + ty + i * 8) * K + kb + tx] = f2bf(tile[tx][ty + i * 8]);
  }
}

// ---------------- K1: small gathers + numeric proj + pools + qterm ----------
__global__ __launch_bounds__(256) void k_gather(
    const int* __restrict__ user_cat, const float* __restrict__ user_num,
    const int* __restrict__ ctx_cat,  const float* __restrict__ ctx_num,
    const int* __restrict__ item_cat, const float* __restrict__ item_num,
    const float* __restrict__ user_emb, const float* __restrict__ item_emb,
    const float* __restrict__ ctx_emb,
    const float* __restrict__ Wu, const float* __restrict__ bu,
    const float* __restrict__ Wi, const float* __restrict__ bi,
    const float* __restrict__ Wc, const float* __restrict__ bc,
    const int* __restrict__ hist_author, const int* __restrict__ hist_tag,
    const int* __restrict__ hist_mask,
    const short* __restrict__ A1s, const float* __restrict__ a1,
    float* __restrict__ base, short* __restrict__ baseb,
    float* __restrict__ qterm)
{
  __shared__ float sRed[8][64];
  __shared__ float sNv[4];
  __shared__ float sQ[64];
  const int b = blockIdx.x, t = threadIdx.x;
  float* out = base + (size_t)b * FEATn;
  short* outb = baseb + (size_t)b * FEATn;

  if (t < 64) sQ[t] = item_emb[(size_t)item_cat[b * 8] * 64 + t];

  for (int f = t; f < 1344; f += 256) {
    float v;
    if (f < 384) {
      int n = f >> 6, e = f & 63;
      int id = user_cat[b * 6 + n];
      v = user_emb[((size_t)n * Vn + id) * 64 + e];
    } else if (f < 896) {
      int g = f - 384; int n = g >> 6, e = g & 63;
      int id = item_cat[b * 8 + n];
      v = item_emb[((size_t)n * Vn + id) * 64 + e];
    } else if (f < 1152) {
      int g = f - 896; int n = g >> 6, e = g & 63;
      int id = ctx_cat[b * 4 + n];
      v = ctx_emb[((size_t)n * Vn + id) * 64 + e];
    } else {
      int g = f - 1152; int wch = g >> 6, e = g & 63;
      float s;
      if (wch == 0) {
        s = bu[e];
        #pragma unroll
        for (int d = 0; d < 8; d++) s += user_num[b * 8 + d] * Wu[d * 64 + e];
      } else if (wch == 1) {
        s = bi[e];
        #pragma unroll
        for (int d = 0; d < 6; d++) s += item_num[b * 6 + d] * Wi[d * 64 + e];
      } else {
        s = bc[e];
        #pragma unroll
        for (int d = 0; d < 4; d++) s += ctx_num[b * 4 + d] * Wc[d * 64 + e];
      }
      v = fmaxf(s, 0.f);
    }
    out[f] = v;
    outb[f] = f2bf(v);
  }

  const float* itemA = item_emb + (size_t)Vn * 64;
  const float* itemT = item_emb + (size_t)7 * Vn * 64;
  const int e = t & 63, wg = t >> 6;
  float aa = 0.f, tg = 0.f, nv = 0.f;
  for (int l = wg; l < Ln; l += 4) {
    if (hist_mask[b * Ln + l] > 0) {      // wave-uniform
      aa += itemA[(size_t)hist_author[b * Ln + l] * 64 + e];
      tg += itemT[(size_t)hist_tag[b * Ln + l] * 64 + e];
      nv += 1.f;
    }
  }
  sRed[wg][e] = aa; sRed[4 + wg][e] = tg;
  if (e == 0) sNv[wg] = nv;
  __syncthreads();
  if (t < 64) {
    float ap = sRed[0][t] + sRed[1][t] + sRed[2][t] + sRed[3][t];
    float tp = sRed[4][t] + sRed[5][t] + sRed[6][t] + sRed[7][t];
    float nvalid = sNv[0] + sNv[1] + sNv[2] + sNv[3];
    float inv = 1.f / fmaxf(nvalid, 1e-6f);
    float apv = ap * inv, tpv = tp * inv;
    out[1408 + t] = apv;  outb[1408 + t] = f2bf(apv);
    out[1472 + t] = tpv;  outb[1472 + t] = f2bf(tpv);
  }

  { // qterm[b][t] = a1[t] + sum_e q[e] * A1sum[e][t]
    float s = a1[t];
    #pragma unroll 8
    for (int ee = 0; ee < 64; ee++) s += sQ[ee] * bf2f(A1s[ee * 256 + t]);
    qterm[(size_t)b * 256 + t] = s;
  }
}

// ---------------- K2a: DIN attention MLP (bf16 MFMA), half-l per block ------
// grid (Bn, 2). blockIdx.y selects l-range [0,128) / [128,224). Scores -> global.
// Softmax + hist_att moved to k_attn_fin (kills the idle-wave tail; LDS 52->36KB).
__global__ __launch_bounds__(256) void k_attn_mlp(
    const int* __restrict__ hist_ids,
    const unsigned* __restrict__ emb0u,
    const short* __restrict__ W1f, const short* __restrict__ W2f,
    const float* __restrict__ qterm,
    const float* __restrict__ a2, const float* __restrict__ A3,
    const float* __restrict__ a3,
    const float* __restrict__ base, float* __restrict__ scoreg)
{
  const int t = threadIdx.x;
  const int w = t >> 6, lane = t & 63, ln = lane & 15, lg = lane >> 4;
  const int b = blockIdx.x;
  const int half = blockIdx.y;
  const int l0g = half * HROWS;
  const int nrow = half ? (LPAD - HROWS) : HROWS;    // 96 : 128
  const int ntile = nrow >> 5;                       // 3 : 4

  __shared__ unsigned sHu[HROWS * 32] __attribute__((aligned(16)));   // 16 KB swz
  __shared__ unsigned sH1u[32 * 128] __attribute__((aligned(16)));    // 16 KB swz
  __shared__ float sScoreW[4][HROWS];
  __shared__ int   sHid[HROWS];
  __shared__ float sQ[64];

  if (t < 64) sQ[t] = base[(size_t)b * FEATn + 384 + t];
  if (t < nrow) {
    int l = l0g + t;
    sHid[t] = (l < Ln) ? hist_ids[b * Ln + l] : -1;
  }
  __syncthreads();

  // stage this half's history rows (interleaved bf16 -> LDS, raw 16B copies)
  for (int u = t; u < nrow * 8; u += 256) {
    int row = u >> 3, seg = (u & 7) << 2;
    int4 hv = make_int4(0, 0, 0, 0);
    int id = sHid[row];
    if (id >= 0) hv = *(const int4*)(emb0u + (size_t)id * 32 + seg);
    *(int4*)(sHu + row * 32 + (seg ^ ((row & 7) << 2))) = hv;
  }

  // per-b fused layer-1 weights (K=64): W1c = W1h + diag(q)*W1q
  s8v bw1c[2][4];
  #pragma unroll
  for (int ks = 0; ks < 2; ks++) {
    float qk[8];
    #pragma unroll
    for (int jj = 0; jj < 8; jj++) qk[jj] = sQ[frag_k(ks, lg, jj)];
    #pragma unroll
    for (int nt = 0; nt < 4; nt++) {
      s8v fh = *(const s8v*)(W1f + (((w * 4 + ks) * 4 + nt) << 9) + lane * 8);
      s8v fq = *(const s8v*)(W1f + (((w * 4 + ks + 2) * 4 + nt) << 9) + lane * 8);
      s8v fc;
      #pragma unroll
      for (int jj = 0; jj < 8; jj++)
        fc[jj] = f2bf(bf2f(fh[jj]) + qk[jj] * bf2f(fq[jj]));
      bw1c[ks][nt] = fc;
    }
  }
  s8v bw2[8][2];
  #pragma unroll
  for (int ks = 0; ks < 8; ks++)
    #pragma unroll
    for (int nt = 0; nt < 2; nt++)
      bw2[ks][nt] = *(const s8v*)(W2f + (((w * 8 + ks) * 2 + nt) << 9) + lane * 8);

  const float a2v0 = a2[w * 32 + ln], a2v1 = a2[w * 32 + 16 + ln];
  const float a3v0 = A3[w * 32 + ln], a3v1 = A3[w * 32 + 16 + ln];
  const float a3s  = a3[0];
  float qt[4];
  #pragma unroll
  for (int i = 0; i < 4; i++)
    qt[i] = qterm[(size_t)b * 256 + w * 64 + i * 16 + ln];
  __syncthreads();

  for (int l0i = 0; l0i < ntile; l0i++) {
    // ---- layer 1 (K=64, fused weights); A-frag = one b128 -----------------
    #pragma unroll
    for (int mt = 0; mt < 2; mt++) {
      f4v acc1[4];
      #pragma unroll
      for (int nt = 0; nt < 4; nt++)
        acc1[nt] = (f4v){qt[nt], qt[nt], qt[nt], qt[nt]};
      {
        int row = l0i * 32 + mt * 16 + ln;
        int swz = (row & 7) << 2;
        const unsigned* rp = sHu + row * 32;
        #pragma unroll
        for (int ks = 0; ks < 2; ks++) {
          s8v hf = *(const s8v*)(rp + ((ks * 16 + lg * 4) ^ swz));
          #pragma unroll
          for (int nt = 0; nt < 4; nt++)
            acc1[nt] = __builtin_amdgcn_mfma_f32_16x16x32_bf16(hf, bw1c[ks][nt], acc1[nt], 0, 0, 0);
        }
      }
      // relu + pack pairs (j, j+16) -> u32
      #pragma unroll
      for (int h = 0; h < 2; h++)
        #pragma unroll
        for (int r = 0; r < 4; r++) {
          int row = mt * 16 + lg * 4 + r;
          int c = (w * 2 + h) * 16 + ln;
          sH1u[row * 128 + (c ^ ((row & 7) << 2))] =
              pk2(fmaxf(acc1[2 * h][r], 0.f), fmaxf(acc1[2 * h + 1][r], 0.f));
        }
    }
    __syncthreads();

    // ---- layer 2 + layer 3 partials ----------------------------------------
    #pragma unroll
    for (int mt = 0; mt < 2; mt++) {
      f4v acc2[2];
      acc2[0] = (f4v){a2v0, a2v0, a2v0, a2v0};
      acc2[1] = (f4v){a2v1, a2v1, a2v1, a2v1};
      {
        int row = mt * 16 + ln;
        int swz = (row & 7) << 2;
        const unsigned* rp = sH1u + row * 128;
        #pragma unroll
        for (int ks = 0; ks < 8; ks++) {
          s8v af = *(const s8v*)(rp + ((ks * 16 + lg * 4) ^ swz));
          acc2[0] = __builtin_amdgcn_mfma_f32_16x16x32_bf16(af, bw2[ks][0], acc2[0], 0, 0, 0);
          acc2[1] = __builtin_amdgcn_mfma_f32_16x16x32_bf16(af, bw2[ks][1], acc2[1], 0, 0, 0);
        }
      }
      #pragma unroll
      for (int r = 0; r < 4; r++) {
        float s = fmaxf(acc2[0][r], 0.f) * a3v0 + fmaxf(acc2[1][r], 0.f) * a3v1;
        s += __shfl_xor(s, 1, 64);
        s += __shfl_xor(s, 2, 64);
        s += __shfl_xor(s, 4, 64);
        s += __shfl_xor(s, 8, 64);
        if (ln == 0) sScoreW[w][l0i * 32 + mt * 16 + lg * 4 + r] = s;
      }
    }
    __syncthreads();                    // sH1u WAR for next tile
  }

  if (t < nrow) {
    float sc = a3s + sScoreW[0][t] + sScoreW[1][t] + sScoreW[2][t] + sScoreW[3][t];
    scoreg[(size_t)b * LPAD + l0g + t] = sc;
  }
}

// ---------------- K2b: softmax + hist_att + tail features -------------------
__global__ __launch_bounds__(256) void k_attn_fin(
    const int* __restrict__ hist_ids, const int* __restrict__ hist_mask,
    const unsigned* __restrict__ emb0u, const float* __restrict__ scoreg,
    float* __restrict__ base, short* __restrict__ baseb)
{
  const int b = blockIdx.x, t = threadIdx.x;
  const int w = t >> 6, lane = t & 63;
  __shared__ float sScore[LPAD];
  __shared__ int   sHid[LPAD];
  __shared__ float sQ[64];
  __shared__ float sRed[4][64];

  if (t < 64) sQ[t] = base[(size_t)b * FEATn + 384 + t];
  if (t < LPAD) sHid[t] = (t < Ln) ? hist_ids[b * Ln + t] : 0;

  if (w == 0) {      // masked softmax on one wave
    float s[4], e[4];
    float mx = -3.0e38f;
    #pragma unroll
    for (int i = 0; i < 4; i++) {
      int l = lane + i * 64;
      bool valid = (l < Ln) && (hist_mask[(size_t)b * Ln + l] > 0);
      s[i] = valid ? scoreg[(size_t)b * LPAD + l] : -3.0e38f;
      mx = fmaxf(mx, s[i]);
    }
    #pragma unroll
    for (int o = 1; o < 64; o <<= 1) mx = fmaxf(mx, __shfl_xor(mx, o, 64));
    float sum = 0.f;
    #pragma unroll
    for (int i = 0; i < 4; i++) {
      e[i] = (s[i] > -1.0e38f) ? expf(s[i] - mx) : 0.f;
      sum += e[i];
    }
    #pragma unroll
    for (int o = 1; o < 64; o <<= 1) sum += __shfl_xor(sum, o, 64);
    float invS = 1.f / fmaxf(sum, 1e-30f);
    #pragma unroll
    for (int i = 0; i < 4; i++) {
      int l = lane + i * 64;
      if (l < LPAD) sScore[l] = e[i] * invS;
    }
  }
  __syncthreads();

  // hist_att straight from L2-hot interleaved table (masked weights exactly 0)
  {
    const int e = t & 63, wg = t >> 6;
    const int c = (e & 15) + ((e >> 5) << 4);
    const int hi = (e >> 4) & 1;
    float aw = 0.f;
    for (int l = wg; l < Ln; l += 4) {
      unsigned v = emb0u[(size_t)sHid[l] * 32 + c];
      short bf = (short)(hi ? (v >> 16) : (v & 0xffffu));
      aw += sScore[l] * bf2f(bf);
    }
    sRed[wg][e] = aw;
  }
  __syncthreads();
  if (t < 64) {
    float ha = sRed[0][t] + sRed[1][t] + sRed[2][t] + sRed[3][t];
    float tv = sQ[t];
    float* out = base + (size_t)b * FEATn;
    short* outb = baseb + (size_t)b * FEATn;
    float v1 = ha, v2 = tv * ha, v3 = tv - ha;
    out[1344 + t] = v1;  outb[1344 + t] = f2bf(v1);
    out[1536 + t] = v2;  outb[1536 + t] = f2bf(v2);
    out[1600 + t] = v3;  outb[1600 + t] = f2bf(v3);
  }
}

// ---------------- K3: bf16 MFMA GEMM, BK=64 + LDS dbuf (1 barrier/step) -----
// A: MxK bf16 row-major. Wt: NxK bf16 row-major. Computes C^T tiles.
__global__ __launch_bounds__(256) void k_gemm_mfma(
    const short* __restrict__ A, const short* __restrict__ Wt,
    const float* __restrict__ bias, void* __restrict__ C,
    int N, int K, int relu, int outbf)
{
  __shared__ short sA[2][64 * 64] __attribute__((aligned(16)));   // 8 KB x2
  __shared__ short sW[2][64 * 64] __attribute__((aligned(16)));
  const int t = threadIdx.x;
  const int w = t >> 6, lane = t & 63, ln = lane & 15, lg = lane >> 4;
  const int m0 = blockIdx.x * 64, n0 = blockIdx.y * 64;
  const int wm = (w & 1) * 32, wn = (w >> 1) * 32;
  const int lr = t >> 3, lc = (t & 7) * 8;          // loader row/col

  f4v acc[2][2] = {{(f4v){0,0,0,0},(f4v){0,0,0,0}},{(f4v){0,0,0,0},(f4v){0,0,0,0}}};
  const int ktn = K >> 6;

  s8v ra0, ra1, rw0, rw1;
  auto loadT = [&](int kt) {
    const short* ap = A + (size_t)(m0 + lr) * K + kt * 64 + lc;
    const short* wp = Wt + (size_t)(n0 + lr) * K + kt * 64 + lc;
    ra0 = *(const s8v*)ap;  ra1 = *(const s8v*)(ap + (size_t)32 * K);
    rw0 = *(const s8v*)wp;  rw1 = *(const s8v*)(wp + (size_t)32 * K);
  };
  auto storeT = [&](int buf) {
    *(s8v*)(sA[buf] + ((lr * 64 + lc) ^ ((lr & 7) << 3))) = ra0;
    *(s8v*)(sA[buf] + (((lr + 32) * 64 + lc) ^ (((lr + 32) & 7) << 3))) = ra1;
    *(s8v*)(sW[buf] + ((lr * 64 + lc) ^ ((lr & 7) << 3))) = rw0;
    *(s8v*)(sW[buf] + (((lr + 32) * 64 + lc) ^ (((lr + 32) & 7) << 3))) = rw1;
  };

  loadT(0); storeT(0);
  __syncthreads();
  int cur = 0;
  for (int kt = 0; kt < ktn; kt++) {
    if (kt + 1 < ktn) loadT(kt + 1);     // prefetch overlaps MFMAs below

    s8v af[2][2], wf[2][2];
    #pragma unroll
    for (int mt = 0; mt < 2; mt++) {
      int row = wm + mt * 16 + ln, swz = (row & 7) << 3;
      #pragma unroll
      for (int ks = 0; ks < 2; ks++) {
        int idx = row * 64 + ks * 32 + lg * 4;
        s4v h0 = *(const s4v*)(sA[cur] + (idx ^ swz));
        s4v h1 = *(const s4v*)(sA[cur] + ((idx + 16) ^ swz));
        af[mt][ks] = __builtin_shufflevector(h0, h1, 0,1,2,3,4,5,6,7);
      }
    }
    #pragma unroll
    for (int ni = 0; ni < 2; ni++) {
      int row = wn + ni * 16 + ln, swz = (row & 7) << 3;
      #pragma unroll
      for (int ks = 0; ks < 2; ks++) {
        int idx = row * 64 + ks * 32 + lg * 4;
        s4v h0 = *(const s4v*)(sW[cur] + (idx ^ swz));
        s4v h1 = *(const s4v*)(sW[cur] + ((idx + 16) ^ swz));
        wf[ni][ks] = __builtin_shufflevector(h0, h1, 0,1,2,3,4,5,6,7);
      }
    }
    #pragma unroll
    for (int mt = 0; mt < 2; mt++)
      #pragma unroll
      for (int ni = 0; ni < 2; ni++)
        #pragma unroll
        for (int ks = 0; ks < 2; ks++)
          acc[mt][ni] = __builtin_amdgcn_mfma_f32_16x16x32_bf16(wf[ni][ks], af[mt][ks], acc[mt][ni], 0, 0, 0);

    if (kt + 1 < ktn) storeT(cur ^ 1);   // ds_write waits vmcnt internally
    __syncthreads();
    cur ^= 1;
  }

  // D[row=n][col=m]: lane(ln,lg): n = wn+ni*16+lg*4+r, m = wm+mt*16+ln
  #pragma unroll
  for (int mt = 0; mt < 2; mt++)
    #pragma unroll
    for (int ni = 0; ni < 2; ni++) {
      int n = n0 + wn + ni * 16 + lg * 4;
      int m = m0 + wm + mt * 16 + ln;
      float4 bz = *(const float4*)(bias + n);
      float4 o;
      o.x = acc[mt][ni][0] + bz.x; o.y = acc[mt][ni][1] + bz.y;
      o.z = acc[mt][ni][2] + bz.z; o.w = acc[mt][ni][3] + bz.w;
      if (relu) {
        o.x = fmaxf(o.x, 0.f); o.y = fmaxf(o.y, 0.f);
        o.z = fmaxf(o.z, 0.f); o.w = fmaxf(o.w, 0.f);
      }
      if (outbf) {
        uint2 p = make_uint2(pk2(o.x, o.y), pk2(o.z, o.w));
        *(uint2*)((short*)C + (size_t)m * N + n) = p;
      } else {
        *(float4*)((float*)C + (size_t)m * N + n) = o;
      }
    }
}

// ---------------- K4: DCN cross (3 iters) + final head ----------------------
__global__ __launch_bounds__(256) void k_cross_final(
    const float* __restrict__ base, const float* __restrict__ cross_w,
    const float* __restrict__ cross_b, const float* __restrict__ deep3,
    const float* __restrict__ Wh, const float* __restrict__ bh,
    float* __restrict__ out)
{
  __shared__ float shred[4];
  const int b = blockIdx.x, t = threadIdx.x;
  const float* br = base + (size_t)b * FEATn;
  float bs[7], xl[7];
  #pragma unroll
  for (int j = 0; j < 7; j++) {
    int i = t + j * 256;
    float v = (i < FEATn) ? br[i] : 0.f;
    bs[j] = v; xl[j] = v;
  }
  for (int k = 0; k < 3; k++) {
    float p = 0.f;
    #pragma unroll
    for (int j = 0; j < 7; j++) {
      int i = t + j * 256;
      if (i < FEATn) p += xl[j] * cross_w[k * FEATn + i];
    }
    float xw = blk_sum(p, shred);
    #pragma unroll
    for (int j = 0; j < 7; j++) {
      int i = t + j * 256;
      if (i < FEATn) xl[j] = bs[j] * xw + cross_b[k * FEATn + i] + xl[j];
    }
  }
  float p = 0.f;
  #pragma unroll
  for (int j = 0; j < 7; j++) {
    int i = t + j * 256;
    if (i < FEATn) p += xl[j] * Wh[i];
  }
  p += deep3[(size_t)b * 256 + t] * Wh[FEATn + t];
  float tot = blk_sum(p, shred);
  if (t == 0) out[b] = tot + bh[0];
}

// ---------------- launch -----------------------------------------------------
extern "C" void kernel_launch(void* const* d_in, const int* in_sizes, int n_in,
                              void* d_out, int out_size, void* d_ws, size_t ws_size,
                              hipStream_t stream) {
  (void)in_sizes; (void)n_in; (void)out_size; (void)ws_size;
  const int*   user_cat  = (const int*)d_in[0];
  const float* user_num  = (const float*)d_in[1];
  const int*   ctx_cat   = (const int*)d_in[2];
  const float* ctx_num   = (const float*)d_in[3];
  const int*   hist_ids  = (const int*)d_in[4];
  const int*   hist_auth = (const int*)d_in[5];
  const int*   hist_tag  = (const int*)d_in[6];
  const int*   hist_mask = (const int*)d_in[7];
  const int*   item_cat  = (const int*)d_in[8];
  const float* item_num  = (const float*)d_in[9];
  const float* user_emb  = (const float*)d_in[10];
  const float* item_emb  = (const float*)d_in[11];
  const float* ctx_emb   = (const float*)d_in[12];
  const float* Wu = (const float*)d_in[13];  const float* bu = (const float*)d_in[14];
  const float* Wi = (const float*)d_in[15];  const float* bi = (const float*)d_in[16];
  const float* Wc = (const float*)d_in[17];  const float* bc = (const float*)d_in[18];
  const float* A1 = (const float*)d_in[19];  const float* a1 = (const float*)d_in[20];
  const float* A2 = (const float*)d_in[21];  const float* a2 = (const float*)d_in[22];
  const float* A3 = (const float*)d_in[23];  const float* a3 = (const float*)d_in[24];
  const float* cross_w = (const float*)d_in[25];
  const float* cross_b = (const float*)d_in[26];
  const float* D1 = (const float*)d_in[27];  const float* d1 = (const float*)d_in[28];
  const float* D2 = (const float*)d_in[29];  const float* d2 = (const float*)d_in[30];
  const float* D3 = (const float*)d_in[31];  const float* d3 = (const float*)d_in[32];
  const float* Wh = (const float*)d_in[33];  const float* bh = (const float*)d_in[34];

  // workspace (all segment sizes keep 16B alignment)
  float* base  = (float*)d_ws;                          // B x 1664 f32
  float* h3    = base + (size_t)Bn * FEATn;             // B x 256 f32
  float* qterm = h3 + (size_t)Bn * 256;                 // B x 256 f32
  float* scoreg = qterm + (size_t)Bn * 256;             // B x 224 f32
  short* baseb = (short*)(scoreg + (size_t)Bn * LPAD);  // B x 1664 bf16
  short* h1b   = baseb + (size_t)Bn * FEATn;            // B x 512 bf16
  short* h2b   = h1b + (size_t)Bn * 512;                // B x 256 bf16
  short* W1f   = h2b + (size_t)Bn * 256;                // 32768
  short* W2f   = W1f + 32768;                           // 32768
  short* A1s   = W2f + 32768;                           // 16384
  unsigned* emb0u = (unsigned*)(A1s + 16384);           // Vn x 32 u32 (interleaved)
  short* D1t   = (short*)(emb0u + (size_t)Vn * 32);     // 512 x 1664
  short* D2t   = D1t + (size_t)512 * 1664;              // 256 x 512
  short* D3t   = D2t + (size_t)256 * 512;               // 256 x 256

  k_prep_all<<<4469, 256, 0, stream>>>(A1, A2, item_emb, D1, D2, D3,
                                       W1f, W2f, A1s, emb0u, D1t, D2t, D3t);
  k_gather<<<Bn, 256, 0, stream>>>(user_cat, user_num, ctx_cat, ctx_num,
                                   item_cat, item_num, user_emb, item_emb, ctx_emb,
                                   Wu, bu, Wi, bi, Wc, bc,
                                   hist_auth, hist_tag, hist_mask,
                                   A1s, a1, base, baseb, qterm);
  k_attn_mlp<<<dim3(Bn, 2), 256, 0, stream>>>(hist_ids, emb0u, W1f, W2f,
                                              qterm, a2, A3, a3, base, scoreg);
  k_attn_fin<<<Bn, 256, 0, stream>>>(hist_ids, hist_mask, emb0u, scoreg,
                                     base, baseb);
  k_gemm_mfma<<<dim3(Bn / 64, 512 / 64), 256, 0, stream>>>(baseb, D1t, d1, h1b, 512, FEATn, 1, 1);
  k_gemm_mfma<<<dim3(Bn / 64, 256 / 64), 256, 0, stream>>>(h1b, D2t, d2, h2b, 256, 512, 1, 1);
  k_gemm_mfma<<<dim3(Bn / 64, 256 / 64), 256, 0, stream>>>(h2b, D3t, d3, h3, 256, 256, 0, 0);
  k_cross_final<<<Bn, 256, 0, stream>>>(base, cross_w, cross_b, h3, Wh, bh,
                                        (float*)d_out);
}

// Round 14
// 209.758 us; speedup vs baseline: 1.0926x; 1.0904x over previous
//
#include <hip/hip_runtime.h>
#include <hip/hip_bf16.h>
#include <math.h>

#define Bn   2048
#define Ln   200
#define En   64
#define Vn   100000
#define FEATn 1664
#define LPAD 224     // 7 * 32

typedef short s4v __attribute__((ext_vector_type(4)));
typedef short s8v __attribute__((ext_vector_type(8)));
typedef float f4v __attribute__((ext_vector_type(4)));

__device__ __forceinline__ short f2bf(float f) {
  union { float f; unsigned u; } v; v.f = f;
  unsigned r = v.u + 0x7FFFu + ((v.u >> 16) & 1u);   // RNE
  return (short)(r >> 16);
}
__device__ __forceinline__ float bf2f(short s) {
  union { unsigned u; float f; } v;
  v.u = ((unsigned)(unsigned short)s) << 16;
  return v.f;
}
__device__ __forceinline__ unsigned pk2(float lo, float hi) {
  __hip_bfloat162 h = __float22bfloat162_rn(make_float2(lo, hi));  // native v_cvt_pk
  union { __hip_bfloat162 h; unsigned u; } c; c.h = h;
  return c.u;
}

// pair-interleaved fragment k-mapping (A and B sides identical -> invariant):
// element jj holds k = ks*32 + lg*4 + (jj>>1) + 16*(jj&1)
__device__ __forceinline__ int frag_k(int ks, int lg, int jj) {
  return ks * 32 + lg * 4 + (jj >> 1) + ((jj & 1) << 4);
}

// ---------------- block-wide sum (256 threads = 4 waves) --------------------
__device__ __forceinline__ float blk_sum(float v, float* shred) {
  #pragma unroll
  for (int o = 32; o > 0; o >>= 1) v += __shfl_down(v, o, 64);
  const int t = threadIdx.x;
  __syncthreads();
  if ((t & 63) == 0) shred[t >> 6] = v;
  __syncthreads();
  return shred[0] + shred[1] + shred[2] + shred[3];
}

// ---------------- K0: merged prep (weights frags + emb cvt + deep transpose) -
__global__ __launch_bounds__(256) void k_prep_all(
    const float* __restrict__ A1, const float* __restrict__ A2,
    const float* __restrict__ item_emb,
    const float* __restrict__ D1, const float* __restrict__ D2,
    const float* __restrict__ D3,
    short* __restrict__ W1f, short* __restrict__ W2f, short* __restrict__ A1s,
    unsigned* __restrict__ emb0u,
    short* __restrict__ T1, short* __restrict__ T2, short* __restrict__ T3)
{
  const int blk = blockIdx.x;
  if (blk < 320) {                       // --- weight fragments + A1sum ---
    int i = blk * 256 + threadIdx.x;
    if (i < 32768) {
      int jj = i & 7, lane = (i >> 3) & 63, nt = (i >> 9) & 3,
          ks = (i >> 11) & 3, w = (i >> 13) & 3;
      int col = w * 64 + nt * 16 + (lane & 15);
      int lg = lane >> 4;
      float v;
      if (ks < 2) {
        int k = frag_k(ks, lg, jj);
        v = A1[(64 + k) * 256 + col] - A1[(128 + k) * 256 + col];
      } else {
        int k = frag_k(ks - 2, lg, jj);
        v = A1[(192 + k) * 256 + col];
      }
      W1f[i] = f2bf(v);
    } else if (i < 65536) {
      int u = i - 32768;
      int jj = u & 7, lane = (u >> 3) & 63, nt = (u >> 9) & 1,
          ks = (u >> 10) & 7, w = (u >> 13) & 3;
      int col = w * 32 + nt * 16 + (lane & 15);
      int lg = lane >> 4;
      int k = frag_k(ks, lg, jj);
      W2f[u] = f2bf(A2[k * 128 + col]);
    } else if (i < 81920) {
      int u = i - 65536;
      int e = u >> 8, j = u & 255;
      A1s[u] = f2bf(A1[e * 256 + j] + A1[(128 + e) * 256 + j]);
    }
  } else if (blk < 3445) {               // --- item_emb table0 -> interleaved bf16
    int q = (blk - 320) * 256 + threadIdx.x;   // q < 800000 exactly
    int row = q >> 3, cq = (q & 7) << 2;
    int e0 = (cq & 15) + ((cq >> 4) << 5);
    const float* rp = item_emb + (size_t)row * 64 + e0;
    float4 lo = *(const float4*)rp;
    float4 hi = *(const float4*)(rp + 16);
    unsigned* d = emb0u + (size_t)row * 32 + cq;
    d[0] = pk2(lo.x, hi.x); d[1] = pk2(lo.y, hi.y);
    d[2] = pk2(lo.z, hi.z); d[3] = pk2(lo.w, hi.w);
  } else {                               // --- D1/D2/D3 [K][N] -> [N][K] bf16
    __shared__ float tile[32][33];
    int b0 = blk - 3445;
    const float* src; short* dst; int K, N;
    if (b0 < 832)      { src = D1; dst = T1; K = 1664; N = 512; }
    else if (b0 < 960) { src = D2; dst = T2; K = 512;  N = 256; b0 -= 832; }
    else               { src = D3; dst = T3; K = 256;  N = 256; b0 -= 960; }
    int nbk = K / 32;
    int kb = (b0 % nbk) * 32, nb = (b0 / nbk) * 32;
    int tx = threadIdx.x & 31, ty = threadIdx.x >> 5;
    #pragma unroll
    for (int i = 0; i < 4; i++)
      tile[ty + i * 8][tx] = src[(size_t)(kb + ty + i * 8) * N + nb + tx];
    __syncthreads();
    #pragma unroll
    for (int i = 0; i < 4; i++)
      dst[(size_t)(nb + ty + i * 8) * K + kb + tx] = f2bf(tile[tx][ty + i * 8]);
  }
}

// ---------------- K1: small gathers + numeric proj + pools + qterm ----------
__global__ __launch_bounds__(256) void k_gather(
    const int* __restrict__ user_cat, const float* __restrict__ user_num,
    const int* __restrict__ ctx_cat,  const float* __restrict__ ctx_num,
    const int* __restrict__ item_cat, const float* __restrict__ item_num,
    const float* __restrict__ user_emb, const float* __restrict__ item_emb,
    const float* __restrict__ ctx_emb,
    const float* __restrict__ Wu, const float* __restrict__ bu,
    const float* __restrict__ Wi, const float* __restrict__ bi,
    const float* __restrict__ Wc, const float* __restrict__ bc,
    const int* __restrict__ hist_author, const int* __restrict__ hist_tag,
    const int* __restrict__ hist_mask,
    const short* __restrict__ A1s, const float* __restrict__ a1,
    float* __restrict__ base, short* __restrict__ baseb,
    float* __restrict__ qterm)
{
  __shared__ float sRed[8][64];
  __shared__ float sNv[4];
  __shared__ float sQ[64];
  const int b = blockIdx.x, t = threadIdx.x;
  float* out = base + (size_t)b * FEATn;
  short* outb = baseb + (size_t)b * FEATn;

  if (t < 64) sQ[t] = item_emb[(size_t)item_cat[b * 8] * 64 + t];

  for (int f = t; f < 1344; f += 256) {
    float v;
    if (f < 384) {
      int n = f >> 6, e = f & 63;
      int id = user_cat[b * 6 + n];
      v = user_emb[((size_t)n * Vn + id) * 64 + e];
    } else if (f < 896) {
      int g = f - 384; int n = g >> 6, e = g & 63;
      int id = item_cat[b * 8 + n];
      v = item_emb[((size_t)n * Vn + id) * 64 + e];
    } else if (f < 1152) {
      int g = f - 896; int n = g >> 6, e = g & 63;
      int id = ctx_cat[b * 4 + n];
      v = ctx_emb[((size_t)n * Vn + id) * 64 + e];
    } else {
      int g = f - 1152; int wch = g >> 6, e = g & 63;
      float s;
      if (wch == 0) {
        s = bu[e];
        #pragma unroll
        for (int d = 0; d < 8; d++) s += user_num[b * 8 + d] * Wu[d * 64 + e];
      } else if (wch == 1) {
        s = bi[e];
        #pragma unroll
        for (int d = 0; d < 6; d++) s += item_num[b * 6 + d] * Wi[d * 64 + e];
      } else {
        s = bc[e];
        #pragma unroll
        for (int d = 0; d < 4; d++) s += ctx_num[b * 4 + d] * Wc[d * 64 + e];
      }
      v = fmaxf(s, 0.f);
    }
    out[f] = v;
    outb[f] = f2bf(v);
  }

  const float* itemA = item_emb + (size_t)Vn * 64;
  const float* itemT = item_emb + (size_t)7 * Vn * 64;
  const int e = t & 63, wg = t >> 6;
  float aa = 0.f, tg = 0.f, nv = 0.f;
  for (int l = wg; l < Ln; l += 4) {
    if (hist_mask[b * Ln + l] > 0) {      // wave-uniform
      aa += itemA[(size_t)hist_author[b * Ln + l] * 64 + e];
      tg += itemT[(size_t)hist_tag[b * Ln + l] * 64 + e];
      nv += 1.f;
    }
  }
  sRed[wg][e] = aa; sRed[4 + wg][e] = tg;
  if (e == 0) sNv[wg] = nv;
  __syncthreads();
  if (t < 64) {
    float ap = sRed[0][t] + sRed[1][t] + sRed[2][t] + sRed[3][t];
    float tp = sRed[4][t] + sRed[5][t] + sRed[6][t] + sRed[7][t];
    float nvalid = sNv[0] + sNv[1] + sNv[2] + sNv[3];
    float inv = 1.f / fmaxf(nvalid, 1e-6f);
    float apv = ap * inv, tpv = tp * inv;
    out[1408 + t] = apv;  outb[1408 + t] = f2bf(apv);
    out[1472 + t] = tpv;  outb[1472 + t] = f2bf(tpv);
  }

  { // qterm[b][t] = a1[t] + sum_e q[e] * A1sum[e][t]
    float s = a1[t];
    #pragma unroll 8
    for (int ee = 0; ee < 64; ee++) s += sQ[ee] * bf2f(A1s[ee * 256 + t]);
    qterm[(size_t)b * 256 + t] = s;
  }
}

// ---------------- K2: fused DIN attention, 8 waves, fused tail --------------
// One b per block, 512 threads. Each wave owns 32 cols of layer-1 N and 16
// cols of layer-2 N: per-wave MFMA & weight-regs halve vs the 4-wave form
// (round-13: VALU-bound serial chain). Cross-wave score reduce overlaps the
// next tile's layer-1. Softmax + hist_att fused (no scoreg round trip).
__global__ __launch_bounds__(512) void k_attn(
    const int* __restrict__ hist_ids, const int* __restrict__ hist_mask,
    const unsigned* __restrict__ emb0u,
    const short* __restrict__ W1f, const short* __restrict__ W2f,
    const float* __restrict__ qterm,
    const float* __restrict__ a2, const float* __restrict__ A3,
    const float* __restrict__ a3,
    float* __restrict__ base, short* __restrict__ baseb)
{
  const int t = threadIdx.x;
  const int w = t >> 6, lane = t & 63, ln = lane & 15, lg = lane >> 4;
  const int b = blockIdx.x;

  __shared__ unsigned sHu[LPAD * 32] __attribute__((aligned(16)));   // 28 KB swz
  __shared__ unsigned sH1u[32 * 128] __attribute__((aligned(16)));   // 16 KB swz
  __shared__ float sScoreW[8][32];                                   // 1 KB
  __shared__ float sScore[LPAD];
  __shared__ int   sHid[LPAD];
  __shared__ float sQ[64];
  __shared__ float sRed[8][64];

  if (t < 64) sQ[t] = base[(size_t)b * FEATn + 384 + t];
  if (t < LPAD) sHid[t] = (t < Ln) ? hist_ids[b * Ln + t] : -1;
  __syncthreads();

  // stage all history rows (interleaved bf16 -> LDS, raw 16B copies)
  for (int u = t; u < LPAD * 8; u += 512) {
    int row = u >> 3, seg = (u & 7) << 2;
    int4 hv = make_int4(0, 0, 0, 0);
    int id = sHid[row];
    if (id >= 0) hv = *(const int4*)(emb0u + (size_t)id * 32 + seg);
    *(int4*)(sHu + row * 32 + (seg ^ ((row & 7) << 2))) = hv;
  }

  // per-b fused layer-1 weights (K=64): W1c = W1h + diag(q)*W1q
  // 8-wave remap onto 4-wave fragment files: w_old = w>>1, nt_old = (w&1)*2+nt
  s8v bw1c[2][2];
  #pragma unroll
  for (int ks = 0; ks < 2; ks++) {
    float qk[8];
    #pragma unroll
    for (int jj = 0; jj < 8; jj++) qk[jj] = sQ[frag_k(ks, lg, jj)];
    #pragma unroll
    for (int nt = 0; nt < 2; nt++) {
      int fidx = (((w >> 1) * 4 + ks) * 4 + ((w & 1) * 2 + nt)) << 9;
      int qidx = (((w >> 1) * 4 + ks + 2) * 4 + ((w & 1) * 2 + nt)) << 9;
      s8v fh = *(const s8v*)(W1f + fidx + lane * 8);
      s8v fq = *(const s8v*)(W1f + qidx + lane * 8);
      s8v fc;
      #pragma unroll
      for (int jj = 0; jj < 8; jj++)
        fc[jj] = f2bf(bf2f(fh[jj]) + qk[jj] * bf2f(fq[jj]));
      bw1c[ks][nt] = fc;
    }
  }
  s8v bw2[8];
  #pragma unroll
  for (int ks = 0; ks < 8; ks++)
    bw2[ks] = *(const s8v*)(W2f + (((((w >> 1) * 8 + ks) * 2) + (w & 1)) << 9) + lane * 8);

  const float a2v = a2[w * 16 + ln];
  const float a3v = A3[w * 16 + ln];
  const float a3s = a3[0];
  float qt[2];
  #pragma unroll
  for (int i = 0; i < 2; i++)
    qt[i] = qterm[(size_t)b * 256 + w * 32 + i * 16 + ln];
  __syncthreads();

  for (int l0i = 0; l0i < 7; l0i++) {
    // ---- layer 1 (K=64, fused weights); A-frag = one b128 -----------------
    #pragma unroll
    for (int mt = 0; mt < 2; mt++) {
      f4v acc1[2];
      acc1[0] = (f4v){qt[0], qt[0], qt[0], qt[0]};
      acc1[1] = (f4v){qt[1], qt[1], qt[1], qt[1]};
      {
        int row = l0i * 32 + mt * 16 + ln;
        int swz = (row & 7) << 2;
        const unsigned* rp = sHu + row * 32;
        #pragma unroll
        for (int ks = 0; ks < 2; ks++) {
          s8v hf = *(const s8v*)(rp + ((ks * 16 + lg * 4) ^ swz));
          acc1[0] = __builtin_amdgcn_mfma_f32_16x16x32_bf16(hf, bw1c[ks][0], acc1[0], 0, 0, 0);
          acc1[1] = __builtin_amdgcn_mfma_f32_16x16x32_bf16(hf, bw1c[ks][1], acc1[1], 0, 0, 0);
        }
      }
      // relu + pack: this wave's (col, col+16) pair -> one u32 per (r)
      #pragma unroll
      for (int r = 0; r < 4; r++) {
        int row = mt * 16 + lg * 4 + r;
        sH1u[row * 128 + ((w * 16 + ln) ^ ((row & 7) << 2))] =
            pk2(fmaxf(acc1[0][r], 0.f), fmaxf(acc1[1][r], 0.f));
      }
    }
    __syncthreads();                    // sH1u ready

    // ---- layer 2 + layer 3 partials ---------------------------------------
    #pragma unroll
    for (int mt = 0; mt < 2; mt++) {
      f4v acc2 = (f4v){a2v, a2v, a2v, a2v};
      {
        int row = mt * 16 + ln;
        int swz = (row & 7) << 2;
        const unsigned* rp = sH1u + row * 128;
        #pragma unroll
        for (int ks = 0; ks < 8; ks++) {
          s8v af = *(const s8v*)(rp + ((ks * 16 + lg * 4) ^ swz));
          acc2 = __builtin_amdgcn_mfma_f32_16x16x32_bf16(af, bw2[ks], acc2, 0, 0, 0);
        }
      }
      #pragma unroll
      for (int r = 0; r < 4; r++) {
        float s = fmaxf(acc2[r], 0.f) * a3v;
        s += __shfl_xor(s, 1, 64);
        s += __shfl_xor(s, 2, 64);
        s += __shfl_xor(s, 4, 64);
        s += __shfl_xor(s, 8, 64);
        if (ln == 0) sScoreW[w][mt * 16 + lg * 4 + r] = s;
      }
    }
    __syncthreads();                    // sScoreW complete; sH1u WAR

    // reducer wave folds this tile's partials, overlapping next tile's L1.
    // Race-free: next sScoreW write is behind the next barrier, which the
    // reducer participates in after finishing these reads.
    if (w == l0i && lane < 32) {
      float sc = a3s;
      #pragma unroll
      for (int k = 0; k < 8; k++) sc += sScoreW[k][lane];
      sScore[l0i * 32 + lane] = sc;
    }
  }
  __syncthreads();

  // ---- masked softmax on wave 0 --------------------------------------------
  if (w == 0) {
    float s[4], e[4];
    float mx = -3.0e38f;
    #pragma unroll
    for (int i = 0; i < 4; i++) {
      int l = lane + i * 64;
      bool valid = (l < Ln) && (hist_mask[(size_t)b * Ln + l] > 0);
      s[i] = valid ? sScore[l] : -3.0e38f;
      mx = fmaxf(mx, s[i]);
    }
    #pragma unroll
    for (int o = 1; o < 64; o <<= 1) mx = fmaxf(mx, __shfl_xor(mx, o, 64));
    float sum = 0.f;
    #pragma unroll
    for (int i = 0; i < 4; i++) {
      e[i] = (s[i] > -1.0e38f) ? expf(s[i] - mx) : 0.f;
      sum += e[i];
    }
    #pragma unroll
    for (int o = 1; o < 64; o <<= 1) sum += __shfl_xor(sum, o, 64);
    float invS = 1.f / fmaxf(sum, 1e-30f);
    #pragma unroll
    for (int i = 0; i < 4; i++) {
      int l = lane + i * 64;
      if (l < LPAD) sScore[l] = e[i] * invS;
    }
  }
  __syncthreads();

  // ---- hist_att from LDS (masked weights exactly 0; interleaved extract) ---
  {
    const int e = t & 63, wg = t >> 6;
    const int c = (e & 15) + ((e >> 5) << 4);
    const int hi = (e >> 4) & 1;
    float aw = 0.f;
    for (int l = wg; l < Ln; l += 8) {
      unsigned v = sHu[l * 32 + (c ^ ((l & 7) << 2))];
      short bf = (short)(hi ? (v >> 16) : (v & 0xffffu));
      aw += sScore[l] * bf2f(bf);
    }
    sRed[wg][e] = aw;
  }
  __syncthreads();
  if (t < 64) {
    float ha = 0.f;
    #pragma unroll
    for (int g = 0; g < 8; g++) ha += sRed[g][t];
    float tv = sQ[t];
    float* out = base + (size_t)b * FEATn;
    short* outb = baseb + (size_t)b * FEATn;
    float v1 = ha, v2 = tv * ha, v3 = tv - ha;
    out[1344 + t] = v1;  outb[1344 + t] = f2bf(v1);
    out[1536 + t] = v2;  outb[1536 + t] = f2bf(v2);
    out[1600 + t] = v3;  outb[1600 + t] = f2bf(v3);
  }
}

// ---------------- K3: bf16 MFMA GEMM, BK=64 + LDS dbuf (1 barrier/step) -----
// A: MxK bf16 row-major. Wt: NxK bf16 row-major. Computes C^T tiles.
__global__ __launch_bounds__(256) void k_gemm_mfma(
    const short* __restrict__ A, const short* __restrict__ Wt,
    const float* __restrict__ bias, void* __restrict__ C,
    int N, int K, int relu, int outbf)
{
  __shared__ short sA[2][64 * 64] __attribute__((aligned(16)));   // 8 KB x2
  __shared__ short sW[2][64 * 64] __attribute__((aligned(16)));
  const int t = threadIdx.x;
  const int w = t >> 6, lane = t & 63, ln = lane & 15, lg = lane >> 4;
  const int m0 = blockIdx.x * 64, n0 = blockIdx.y * 64;
  const int wm = (w & 1) * 32, wn = (w >> 1) * 32;
  const int lr = t >> 3, lc = (t & 7) * 8;          // loader row/col

  f4v acc[2][2] = {{(f4v){0,0,0,0},(f4v){0,0,0,0}},{(f4v){0,0,0,0},(f4v){0,0,0,0}}};
  const int ktn = K >> 6;

  s8v ra0, ra1, rw0, rw1;
  auto loadT = [&](int kt) {
    const short* ap = A + (size_t)(m0 + lr) * K + kt * 64 + lc;
    const short* wp = Wt + (size_t)(n0 + lr) * K + kt * 64 + lc;
    ra0 = *(const s8v*)ap;  ra1 = *(const s8v*)(ap + (size_t)32 * K);
    rw0 = *(const s8v*)wp;  rw1 = *(const s8v*)(wp + (size_t)32 * K);
  };
  auto storeT = [&](int buf) {
    *(s8v*)(sA[buf] + ((lr * 64 + lc) ^ ((lr & 7) << 3))) = ra0;
    *(s8v*)(sA[buf] + (((lr + 32) * 64 + lc) ^ (((lr + 32) & 7) << 3))) = ra1;
    *(s8v*)(sW[buf] + ((lr * 64 + lc) ^ ((lr & 7) << 3))) = rw0;
    *(s8v*)(sW[buf] + (((lr + 32) * 64 + lc) ^ (((lr + 32) & 7) << 3))) = rw1;
  };

  loadT(0); storeT(0);
  __syncthreads();
  int cur = 0;
  for (int kt = 0; kt < ktn; kt++) {
    if (kt + 1 < ktn) loadT(kt + 1);     // prefetch overlaps MFMAs below

    s8v af[2][2], wf[2][2];
    #pragma unroll
    for (int mt = 0; mt < 2; mt++) {
      int row = wm + mt * 16 + ln, swz = (row & 7) << 3;
      #pragma unroll
      for (int ks = 0; ks < 2; ks++) {
        int idx = row * 64 + ks * 32 + lg * 4;
        s4v h0 = *(const s4v*)(sA[cur] + (idx ^ swz));
        s4v h1 = *(const s4v*)(sA[cur] + ((idx + 16) ^ swz));
        af[mt][ks] = __builtin_shufflevector(h0, h1, 0,1,2,3,4,5,6,7);
      }
    }
    #pragma unroll
    for (int ni = 0; ni < 2; ni++) {
      int row = wn + ni * 16 + ln, swz = (row & 7) << 3;
      #pragma unroll
      for (int ks = 0; ks < 2; ks++) {
        int idx = row * 64 + ks * 32 + lg * 4;
        s4v h0 = *(const s4v*)(sW[cur] + (idx ^ swz));
        s4v h1 = *(const s4v*)(sW[cur] + ((idx + 16) ^ swz));
        wf[ni][ks] = __builtin_shufflevector(h0, h1, 0,1,2,3,4,5,6,7);
      }
    }
    #pragma unroll
    for (int mt = 0; mt < 2; mt++)
      #pragma unroll
      for (int ni = 0; ni < 2; ni++)
        #pragma unroll
        for (int ks = 0; ks < 2; ks++)
          acc[mt][ni] = __builtin_amdgcn_mfma_f32_16x16x32_bf16(wf[ni][ks], af[mt][ks], acc[mt][ni], 0, 0, 0);

    if (kt + 1 < ktn) storeT(cur ^ 1);   // ds_write waits vmcnt internally
    __syncthreads();
    cur ^= 1;
  }

  // D[row=n][col=m]: lane(ln,lg): n = wn+ni*16+lg*4+r, m = wm+mt*16+ln
  #pragma unroll
  for (int mt = 0; mt < 2; mt++)
    #pragma unroll
    for (int ni = 0; ni < 2; ni++) {
      int n = n0 + wn + ni * 16 + lg * 4;
      int m = m0 + wm + mt * 16 + ln;
      float4 bz = *(const float4*)(bias + n);
      float4 o;
      o.x = acc[mt][ni][0] + bz.x; o.y = acc[mt][ni][1] + bz.y;
      o.z = acc[mt][ni][2] + bz.z; o.w = acc[mt][ni][3] + bz.w;
      if (relu) {
        o.x = fmaxf(o.x, 0.f); o.y = fmaxf(o.y, 0.f);
        o.z = fmaxf(o.z, 0.f); o.w = fmaxf(o.w, 0.f);
      }
      if (outbf) {
        uint2 p = make_uint2(pk2(o.x, o.y), pk2(o.z, o.w));
        *(uint2*)((short*)C + (size_t)m * N + n) = p;
      } else {
        *(float4*)((float*)C + (size_t)m * N + n) = o;
      }
    }
}

// ---------------- K4: DCN cross (3 iters) + final head ----------------------
__global__ __launch_bounds__(256) void k_cross_final(
    const float* __restrict__ base, const float* __restrict__ cross_w,
    const float* __restrict__ cross_b, const float* __restrict__ deep3,
    const float* __restrict__ Wh, const float* __restrict__ bh,
    float* __restrict__ out)
{
  __shared__ float shred[4];
  const int b = blockIdx.x, t = threadIdx.x;
  const float* br = base + (size_t)b * FEATn;
  float bs[7], xl[7];
  #pragma unroll
  for (int j = 0; j < 7; j++) {
    int i = t + j * 256;
    float v = (i < FEATn) ? br[i] : 0.f;
    bs[j] = v; xl[j] = v;
  }
  for (int k = 0; k < 3; k++) {
    float p = 0.f;
    #pragma unroll
    for (int j = 0; j < 7; j++) {
      int i = t + j * 256;
      if (i < FEATn) p += xl[j] * cross_w[k * FEATn + i];
    }
    float xw = blk_sum(p, shred);
    #pragma unroll
    for (int j = 0; j < 7; j++) {
      int i = t + j * 256;
      if (i < FEATn) xl[j] = bs[j] * xw + cross_b[k * FEATn + i] + xl[j];
    }
  }
  float p = 0.f;
  #pragma unroll
  for (int j = 0; j < 7; j++) {
    int i = t + j * 256;
    if (i < FEATn) p += xl[j] * Wh[i];
  }
  p += deep3[(size_t)b * 256 + t] * Wh[FEATn + t];
  float tot = blk_sum(p, shred);
  if (t == 0) out[b] = tot + bh[0];
}

// ---------------- launch -----------------------------------------------------
extern "C" void kernel_launch(void* const* d_in, const int* in_sizes, int n_in,
                              void* d_out, int out_size, void* d_ws, size_t ws_size,
                              hipStream_t stream) {
  (void)in_sizes; (void)n_in; (void)out_size; (void)ws_size;
  const int*   user_cat  = (const int*)d_in[0];
  const float* user_num  = (const float*)d_in[1];
  const int*   ctx_cat   = (const int*)d_in[2];
  const float* ctx_num   = (const float*)d_in[3];
  const int*   hist_ids  = (const int*)d_in[4];
  const int*   hist_auth = (const int*)d_in[5];
  const int*   hist_tag  = (const int*)d_in[6];
  const int*   hist_mask = (const int*)d_in[7];
  const int*   item_cat  = (const int*)d_in[8];
  const float* item_num  = (const float*)d_in[9];
  const float* user_emb  = (const float*)d_in[10];
  const float* item_emb  = (const float*)d_in[11];
  const float* ctx_emb   = (const float*)d_in[12];
  const float* Wu = (const float*)d_in[13];  const float* bu = (const float*)d_in[14];
  const float* Wi = (const float*)d_in[15];  const float* bi = (const float*)d_in[16];
  const float* Wc = (const float*)d_in[17];  const float* bc = (const float*)d_in[18];
  const float* A1 = (const float*)d_in[19];  const float* a1 = (const float*)d_in[20];
  const float* A2 = (const float*)d_in[21];  const float* a2 = (const float*)d_in[22];
  const float* A3 = (const float*)d_in[23];  const float* a3 = (const float*)d_in[24];
  const float* cross_w = (const float*)d_in[25];
  const float* cross_b = (const float*)d_in[26];
  const float* D1 = (const float*)d_in[27];  const float* d1 = (const float*)d_in[28];
  const float* D2 = (const float*)d_in[29];  const float* d2 = (const float*)d_in[30];
  const float* D3 = (const float*)d_in[31];  const float* d3 = (const float*)d_in[32];
  const float* Wh = (const float*)d_in[33];  const float* bh = (const float*)d_in[34];

  // workspace (all segment sizes keep 16B alignment)
  float* base  = (float*)d_ws;                          // B x 1664 f32
  float* h3    = base + (size_t)Bn * FEATn;             // B x 256 f32
  float* qterm = h3 + (size_t)Bn * 256;                 // B x 256 f32
  short* baseb = (short*)(qterm + (size_t)Bn * 256);    // B x 1664 bf16
  short* h1b   = baseb + (size_t)Bn * FEATn;            // B x 512 bf16
  short* h2b   = h1b + (size_t)Bn * 512;                // B x 256 bf16
  short* W1f   = h2b + (size_t)Bn * 256;                // 32768
  short* W2f   = W1f + 32768;                           // 32768
  short* A1s   = W2f + 32768;                           // 16384
  unsigned* emb0u = (unsigned*)(A1s + 16384);           // Vn x 32 u32 (interleaved)
  short* D1t   = (short*)(emb0u + (size_t)Vn * 32);     // 512 x 1664
  short* D2t   = D1t + (size_t)512 * 1664;              // 256 x 512
  short* D3t   = D2t + (size_t)256 * 512;               // 256 x 256

  k_prep_all<<<4469, 256, 0, stream>>>(A1, A2, item_emb, D1, D2, D3,
                                       W1f, W2f, A1s, emb0u, D1t, D2t, D3t);
  k_gather<<<Bn, 256, 0, stream>>>(user_cat, user_num, ctx_cat, ctx_num,
                                   item_cat, item_num, user_emb, item_emb, ctx_emb,
                                   Wu, bu, Wi, bi, Wc, bc,
                                   hist_auth, hist_tag, hist_mask,
                                   A1s, a1, base, baseb, qterm);
  k_attn<<<Bn, 512, 0, stream>>>(hist_ids, hist_mask, emb0u,
                                 W1f, W2f, qterm, a2, A3, a3, base, baseb);
  k_gemm_mfma<<<dim3(Bn / 64, 512 / 64), 256, 0, stream>>>(baseb, D1t, d1, h1b, 512, FEATn, 1, 1);
  k_gemm_mfma<<<dim3(Bn / 64, 256 / 64), 256, 0, stream>>>(h1b, D2t, d2, h2b, 256, 512, 1, 1);
  k_gemm_mfma<<<dim3(Bn / 64, 256 / 64), 256, 0, stream>>>(h2b, D3t, d3, h3, 256, 256, 0, 0);
  k_cross_final<<<Bn, 256, 0, stream>>>(base, cross_w, cross_b, h3, Wh, bh,
                                        (float*)d_out);
}